// Round 1
// baseline (954.366 us; speedup 1.0000x reference)
//
#include <hip/hip_runtime.h>

// SGC (Simplified Graph Conv) forward:
//   h = relu( prop(x)  @ W1^T + b1 )
//   h = relu( prop(h)  @ W2^T + b2 )
//   out =      h        @ W3^T + b3
// prop(x)[d] = sum_{edges (s,d)} dinv[s]*dinv[d]*x[s] + dinv[d]^2 * x[d]
// dinv[i] = rsqrt(indeg[i] + 1)   (self-loop included in degree)

#define F 64
#define C 16

// ---- degree via atomics (deg accumulated as float; counts <= E fit exactly) ----
__global__ void deg_kernel(const int* __restrict__ dst, float* __restrict__ deg, int E) {
    int i = blockIdx.x * blockDim.x + threadIdx.x;
    if (i < E) atomicAdd(&deg[dst[i]], 1.0f);
}

// in-place: deg -> rsqrt(deg + 1)
__global__ void rsqrt_kernel(float* __restrict__ d, int n) {
    int i = blockIdx.x * blockDim.x + threadIdx.x;
    if (i < n) d[i] = rsqrtf(d[i] + 1.0f);
}

// ---- scatter propagate: one wave (64 lanes) per edge, lane = feature ----
__global__ void scatter_kernel(const int* __restrict__ src, const int* __restrict__ dst,
                               const float* __restrict__ dinv, const float* __restrict__ xin,
                               float* __restrict__ out, int E) {
    long long t = (long long)blockIdx.x * blockDim.x + threadIdx.x;
    int e = (int)(t >> 6);
    if (e >= E) return;
    int f = (int)t & 63;
    int s = src[e];
    int d = dst[e];
    float norm = dinv[s] * dinv[d];                      // wave-uniform
    float v = norm * xin[(long long)s * F + f];          // coalesced 256B gather
    atomicAdd(out + (long long)d * F + f, v);            // coalesced 256B atomic
}

// ---- h1 = relu( (prop + dinv^2 * x) @ W1^T + b1 ), 4 nodes/block, wave/node ----
__global__ __launch_bounds__(256) void lin1_kernel(
    const float* __restrict__ prop, const float* __restrict__ xin,
    const float* __restrict__ dinv, const float* __restrict__ W1,
    const float* __restrict__ b1, float* __restrict__ h1, int n) {
    __shared__ float sWT[F][F + 1];   // transposed + padded: conflict-free both ways
    __shared__ float sIn[4][F];
    int tid = threadIdx.x;
    for (int i = tid; i < F * F; i += 256) {
        int j = i >> 6, k = i & 63;
        sWT[k][j] = W1[i];            // sWT[k][j] = W1[j][k]
    }
    int w = tid >> 6, j = tid & 63;
    int node = blockIdx.x * 4 + w;
    if (node < n) {
        float dd = dinv[node]; dd *= dd;
        sIn[w][j] = prop[(long long)node * F + j] + dd * xin[(long long)node * F + j];
    }
    __syncthreads();
    if (node < n) {
        float acc = b1[j];
#pragma unroll
        for (int k = 0; k < F; ++k) acc = fmaf(sIn[w][k], sWT[k][j], acc);
        h1[(long long)node * F + j] = fmaxf(acc, 0.0f);
    }
}

// ---- out = relu( (prop + dinv^2*h1) @ W2^T + b2 ) @ W3^T + b3 ; h2 stays in LDS ----
__global__ __launch_bounds__(256) void lin23_kernel(
    const float* __restrict__ prop, const float* __restrict__ h1,
    const float* __restrict__ dinv, const float* __restrict__ W2,
    const float* __restrict__ b2, const float* __restrict__ W3,
    const float* __restrict__ b3, float* __restrict__ out, int n) {
    __shared__ float sW2T[F][F + 1];
    __shared__ float sW3T[F][C + 1];  // sW3T[j][c] = W3[c][j]
    __shared__ float sIn[4][F];
    __shared__ float sH2[4][F];
    int tid = threadIdx.x;
    for (int i = tid; i < F * F; i += 256) {
        int j = i >> 6, k = i & 63;
        sW2T[k][j] = W2[i];
    }
    for (int i = tid; i < C * F; i += 256) {
        int c = i >> 6, j = i & 63;
        sW3T[j][c] = W3[i];
    }
    int w = tid >> 6, j = tid & 63;
    int node = blockIdx.x * 4 + w;
    if (node < n) {
        float dd = dinv[node]; dd *= dd;
        sIn[w][j] = prop[(long long)node * F + j] + dd * h1[(long long)node * F + j];
    }
    __syncthreads();
    if (node < n) {
        float acc = b2[j];
#pragma unroll
        for (int k = 0; k < F; ++k) acc = fmaf(sIn[w][k], sW2T[k][j], acc);
        sH2[w][j] = fmaxf(acc, 0.0f);
    }
    __syncthreads();
    if (node < n && j < C) {
        float acc = b3[j];
#pragma unroll
        for (int k = 0; k < F; ++k) acc = fmaf(sH2[w][k], sW3T[k][j], acc);
        out[(long long)node * C + j] = acc;
    }
}

extern "C" void kernel_launch(void* const* d_in, const int* in_sizes, int n_in,
                              void* d_out, int out_size, void* d_ws, size_t ws_size,
                              hipStream_t stream) {
    const float* x  = (const float*)d_in[0];
    const int* edge = (const int*)d_in[1];   // harness delivers integer inputs as int32
    const float* W1 = (const float*)d_in[2];
    const float* b1 = (const float*)d_in[3];
    const float* W2 = (const float*)d_in[4];
    const float* b2 = (const float*)d_in[5];
    const float* W3 = (const float*)d_in[6];
    const float* b3 = (const float*)d_in[7];
    float* out = (float*)d_out;

    int n = in_sizes[0] / F;        // 100000
    int E = in_sizes[1] / 2;        // 1600000
    const int* src = edge;
    const int* dst = edge + E;

    // workspace layout (floats): dinv[n] | buf[n*F] | h1[n*F]  (~52 MB)
    float* ws = (float*)d_ws;
    size_t o = 0;
    float* dinv = ws + o; o += ((size_t)n + 255) & ~(size_t)255;
    float* buf  = ws + o; o += (size_t)n * F;
    float* h1   = ws + o;

    hipMemsetAsync(dinv, 0, (size_t)n * sizeof(float), stream);
    hipMemsetAsync(buf,  0, (size_t)n * F * sizeof(float), stream);

    deg_kernel<<<(E + 255) / 256, 256, 0, stream>>>(dst, dinv, E);
    rsqrt_kernel<<<(n + 255) / 256, 256, 0, stream>>>(dinv, n);

    // propagate 1: x -> buf
    long long sthreads = (long long)E * 64;
    int sblocks = (int)((sthreads + 255) / 256);
    scatter_kernel<<<sblocks, 256, 0, stream>>>(src, dst, dinv, x, buf, E);

    // h1 = relu(lin1(buf + selfloop(x)))
    lin1_kernel<<<(n + 3) / 4, 256, 0, stream>>>(buf, x, dinv, W1, b1, h1, n);

    // propagate 2: h1 -> buf (re-zero first)
    hipMemsetAsync(buf, 0, (size_t)n * F * sizeof(float), stream);
    scatter_kernel<<<sblocks, 256, 0, stream>>>(src, dst, dinv, h1, buf, E);

    // out = lin3(relu(lin2(buf + selfloop(h1))))
    lin23_kernel<<<(n + 3) / 4, 256, 0, stream>>>(buf, h1, dinv, W2, b2, W3, b3, out, n);
}

// Round 2
// 498.999 us; speedup vs baseline: 1.9126x; 1.9126x over previous
//
#include <hip/hip_runtime.h>

// SGC forward via device-built CSR + gather propagation (no f32 atomics).
//   prop(x)[d] = sum_{(s,d)} dinv[s]*dinv[d]*x[s] + dinv[d]^2 * x[d]
//   dinv[i] = rsqrt(indeg[i] + 1)
//   h1 = relu(prop(x) @ W1^T + b1); out = relu(prop(h1) @ W2^T + b2) @ W3^T + b3

#define F 64
#define C 16
#define SCAN_B 1024   // elements per scan block (256 threads x 4)

// ---- degree histogram (int atomics) ----
__global__ void deg_kernel(const int* __restrict__ dst, int* __restrict__ deg, int E) {
    int i = blockIdx.x * blockDim.x + threadIdx.x;
    if (i < E) atomicAdd(&deg[dst[i]], 1);
}

__global__ void dinv_kernel(const int* __restrict__ deg, float* __restrict__ dinv, int n) {
    int i = blockIdx.x * blockDim.x + threadIdx.x;
    if (i < n) dinv[i] = rsqrtf((float)deg[i] + 1.0f);
}

// ---- exclusive scan of deg -> rowptr (3 kernels) ----
__global__ __launch_bounds__(256) void scan1_kernel(const int* __restrict__ deg,
                                                    int* __restrict__ part,
                                                    int* __restrict__ bsum, int n) {
    __shared__ int ts[256];
    int b = blockIdx.x, t = threadIdx.x;
    int base = b * SCAN_B + t * 4;
    int v[4], sum = 0;
#pragma unroll
    for (int k = 0; k < 4; ++k) { int i = base + k; v[k] = (i < n) ? deg[i] : 0; sum += v[k]; }
    ts[t] = sum;
    __syncthreads();
    for (int off = 1; off < 256; off <<= 1) {
        int add = (t >= off) ? ts[t - off] : 0;
        __syncthreads();
        ts[t] += add;
        __syncthreads();
    }
    int run = ts[t] - sum;  // exclusive prefix of this thread's chunk within block
#pragma unroll
    for (int k = 0; k < 4; ++k) { int i = base + k; if (i < n) part[i] = run; run += v[k]; }
    if (t == 255) bsum[b] = ts[255];
}

__global__ __launch_bounds__(256) void scan2_kernel(int* __restrict__ bsum, int nb) {
    __shared__ int ts[256];
    int t = threadIdx.x;
    int v = (t < nb) ? bsum[t] : 0;
    ts[t] = v;
    __syncthreads();
    for (int off = 1; off < 256; off <<= 1) {
        int add = (t >= off) ? ts[t - off] : 0;
        __syncthreads();
        ts[t] += add;
        __syncthreads();
    }
    if (t < nb) bsum[t] = ts[t] - v;  // exclusive
}

__global__ void scan3_kernel(const int* __restrict__ part, const int* __restrict__ bsum,
                             int* __restrict__ rowptr, int n, int E) {
    int i = blockIdx.x * blockDim.x + threadIdx.x;
    if (i < n) rowptr[i] = part[i] + bsum[i / SCAN_B];
    if (i == 0) rowptr[n] = E;
}

// ---- bucket fill: csr_src[rowptr[d] + cursor++] = src ----
__global__ void fill_kernel(const int* __restrict__ src, const int* __restrict__ dst,
                            int* __restrict__ cursor, int* __restrict__ csr_src, int E) {
    int e = blockIdx.x * blockDim.x + threadIdx.x;
    if (e < E) {
        int pos = atomicAdd(&cursor[dst[e]], 1);
        csr_src[pos] = src[e];
    }
}

// ---- fused gather-propagate + linear(+relu): wave per node, lane = feature ----
__global__ __launch_bounds__(256) void prop_lin1_kernel(
    const float* __restrict__ x, const int* __restrict__ rowptr,
    const int* __restrict__ csr_src, const float* __restrict__ dinv,
    const float* __restrict__ W1, const float* __restrict__ b1,
    float* __restrict__ h1, int n) {
    __shared__ float sWT[F][F + 1];
    __shared__ float sIn[4][F];
    int tid = threadIdx.x;
    for (int i = tid; i < F * F; i += 256) {
        int j = i >> 6, k = i & 63;
        sWT[k][j] = W1[i];
    }
    int w = tid >> 6, f = tid & 63;
    int node = blockIdx.x * 4 + w;
    if (node < n) {
        int beg = rowptr[node], end = rowptr[node + 1];
        float acc = 0.0f;
        int p = beg;
        for (; p + 4 <= end; p += 4) {
            int s0 = csr_src[p], s1 = csr_src[p + 1], s2 = csr_src[p + 2], s3 = csr_src[p + 3];
            float x0 = x[(size_t)s0 * F + f], x1 = x[(size_t)s1 * F + f];
            float x2 = x[(size_t)s2 * F + f], x3 = x[(size_t)s3 * F + f];
            acc = fmaf(dinv[s0], x0, acc); acc = fmaf(dinv[s1], x1, acc);
            acc = fmaf(dinv[s2], x2, acc); acc = fmaf(dinv[s3], x3, acc);
        }
        for (; p < end; ++p) {
            int s = csr_src[p];
            acc = fmaf(dinv[s], x[(size_t)s * F + f], acc);
        }
        float dd = dinv[node];
        sIn[w][f] = dd * acc + dd * dd * x[(size_t)node * F + f];
    }
    __syncthreads();
    if (node < n) {
        float acc = b1[f];
#pragma unroll
        for (int k = 0; k < F; ++k) acc = fmaf(sIn[w][k], sWT[k][f], acc);
        h1[(size_t)node * F + f] = fmaxf(acc, 0.0f);
    }
}

// ---- fused gather-propagate + lin2 + relu + lin3 ----
__global__ __launch_bounds__(256) void prop_lin23_kernel(
    const float* __restrict__ h1, const int* __restrict__ rowptr,
    const int* __restrict__ csr_src, const float* __restrict__ dinv,
    const float* __restrict__ W2, const float* __restrict__ b2,
    const float* __restrict__ W3, const float* __restrict__ b3,
    float* __restrict__ out, int n) {
    __shared__ float sW2T[F][F + 1];
    __shared__ float sW3T[F][C + 1];
    __shared__ float sIn[4][F];
    __shared__ float sH2[4][F];
    int tid = threadIdx.x;
    for (int i = tid; i < F * F; i += 256) {
        int j = i >> 6, k = i & 63;
        sW2T[k][j] = W2[i];
    }
    for (int i = tid; i < C * F; i += 256) {
        int c = i >> 6, j = i & 63;
        sW3T[j][c] = W3[i];
    }
    int w = tid >> 6, f = tid & 63;
    int node = blockIdx.x * 4 + w;
    if (node < n) {
        int beg = rowptr[node], end = rowptr[node + 1];
        float acc = 0.0f;
        int p = beg;
        for (; p + 4 <= end; p += 4) {
            int s0 = csr_src[p], s1 = csr_src[p + 1], s2 = csr_src[p + 2], s3 = csr_src[p + 3];
            float x0 = h1[(size_t)s0 * F + f], x1 = h1[(size_t)s1 * F + f];
            float x2 = h1[(size_t)s2 * F + f], x3 = h1[(size_t)s3 * F + f];
            acc = fmaf(dinv[s0], x0, acc); acc = fmaf(dinv[s1], x1, acc);
            acc = fmaf(dinv[s2], x2, acc); acc = fmaf(dinv[s3], x3, acc);
        }
        for (; p < end; ++p) {
            int s = csr_src[p];
            acc = fmaf(dinv[s], h1[(size_t)s * F + f], acc);
        }
        float dd = dinv[node];
        sIn[w][f] = dd * acc + dd * dd * h1[(size_t)node * F + f];
    }
    __syncthreads();
    if (node < n) {
        float acc = b2[f];
#pragma unroll
        for (int k = 0; k < F; ++k) acc = fmaf(sIn[w][k], sW2T[k][f], acc);
        sH2[w][f] = fmaxf(acc, 0.0f);
    }
    __syncthreads();
    if (node < n && f < C) {
        float acc = b3[f];
#pragma unroll
        for (int k = 0; k < F; ++k) acc = fmaf(sH2[w][k], sW3T[k][f], acc);
        out[(size_t)node * C + f] = acc;
    }
}

extern "C" void kernel_launch(void* const* d_in, const int* in_sizes, int n_in,
                              void* d_out, int out_size, void* d_ws, size_t ws_size,
                              hipStream_t stream) {
    const float* x  = (const float*)d_in[0];
    const int* edge = (const int*)d_in[1];
    const float* W1 = (const float*)d_in[2];
    const float* b1 = (const float*)d_in[3];
    const float* W2 = (const float*)d_in[4];
    const float* b2 = (const float*)d_in[5];
    const float* W3 = (const float*)d_in[6];
    const float* b3 = (const float*)d_in[7];
    float* out = (float*)d_out;

    int n = in_sizes[0] / F;        // 100000
    int E = in_sizes[1] / 2;        // 1600000
    const int* src = edge;
    const int* dst = edge + E;

    int nb = (n + SCAN_B - 1) / SCAN_B;   // scan blocks (98)

    // workspace layout
    char* ws = (char*)d_ws;
    size_t o = 0;
    auto alloc = [&](size_t bytes) { char* p = ws + o; o += (bytes + 255) & ~(size_t)255; return p; };
    int*   deg     = (int*)  alloc((size_t)n * 4);
    int*   part    = (int*)  alloc((size_t)n * 4);
    int*   bsum    = (int*)  alloc(256 * 4);
    int*   rowptr  = (int*)  alloc((size_t)(n + 1) * 4);
    int*   cursor  = (int*)  alloc((size_t)n * 4);
    int*   csr_src = (int*)  alloc((size_t)E * 4);
    float* dinv    = (float*)alloc((size_t)n * 4);
    float* h1      = (float*)alloc((size_t)n * F * 4);

    hipMemsetAsync(deg, 0, (size_t)n * 4, stream);
    deg_kernel<<<(E + 255) / 256, 256, 0, stream>>>(dst, deg, E);
    dinv_kernel<<<(n + 255) / 256, 256, 0, stream>>>(deg, dinv, n);

    scan1_kernel<<<nb, 256, 0, stream>>>(deg, part, bsum, n);
    scan2_kernel<<<1, 256, 0, stream>>>(bsum, nb);
    scan3_kernel<<<(n + 255) / 256, 256, 0, stream>>>(part, bsum, rowptr, n, E);

    hipMemcpyAsync(cursor, rowptr, (size_t)n * 4, hipMemcpyDeviceToDevice, stream);
    fill_kernel<<<(E + 255) / 256, 256, 0, stream>>>(src, dst, cursor, csr_src, E);

    prop_lin1_kernel<<<(n + 3) / 4, 256, 0, stream>>>(x, rowptr, csr_src, dinv, W1, b1, h1, n);
    prop_lin23_kernel<<<(n + 3) / 4, 256, 0, stream>>>(h1, rowptr, csr_src, dinv, W2, b2, W3, b3, out, n);
}

// Round 3
// 446.637 us; speedup vs baseline: 2.1368x; 1.1172x over previous
//
#include <hip/hip_runtime.h>

// SGC forward via device-built CSR + quarter-wave float4 gather propagation.
//   dinv[i] = rsqrt(indeg[i] + 1)
//   prop(x)[d] = dinv[d] * ( sum_{(s,d)} dinv[s]*x[s] + dinv[d]*x[d] )
//   h1s = dinv .* relu(prop(x) @ W1^T + b1)           (stored pre-scaled)
//   prop2[d] = dinv[d] * ( sum h1s[s] + h1s[d] )      (pure adds)
//   out = relu(prop2 @ W2^T + b2) @ W3^T + b3

#define F 64
#define C 16
#define SCAN_B 1024

// ---- degree histogram (int atomics), 4 edges/thread ----
__global__ void deg_kernel(const int* __restrict__ dst, int* __restrict__ deg, int E) {
    int i = (blockIdx.x * blockDim.x + threadIdx.x) * 4;
#pragma unroll
    for (int k = 0; k < 4; ++k)
        if (i + k < E) atomicAdd(&deg[dst[i + k]], 1);
}

__global__ void dinv_kernel(const int* __restrict__ deg, float* __restrict__ dinv, int n) {
    int i = blockIdx.x * blockDim.x + threadIdx.x;
    if (i < n) dinv[i] = rsqrtf((float)deg[i] + 1.0f);
}

// ---- exclusive scan of deg -> rowptr (3 kernels) ----
__global__ __launch_bounds__(256) void scan1_kernel(const int* __restrict__ deg,
                                                    int* __restrict__ part,
                                                    int* __restrict__ bsum, int n) {
    __shared__ int ts[256];
    int b = blockIdx.x, t = threadIdx.x;
    int base = b * SCAN_B + t * 4;
    int v[4], sum = 0;
#pragma unroll
    for (int k = 0; k < 4; ++k) { int i = base + k; v[k] = (i < n) ? deg[i] : 0; sum += v[k]; }
    ts[t] = sum;
    __syncthreads();
    for (int off = 1; off < 256; off <<= 1) {
        int add = (t >= off) ? ts[t - off] : 0;
        __syncthreads();
        ts[t] += add;
        __syncthreads();
    }
    int run = ts[t] - sum;
#pragma unroll
    for (int k = 0; k < 4; ++k) { int i = base + k; if (i < n) part[i] = run; run += v[k]; }
    if (t == 255) bsum[b] = ts[255];
}

__global__ __launch_bounds__(256) void scan2_kernel(int* __restrict__ bsum, int nb) {
    __shared__ int ts[256];
    int t = threadIdx.x;
    int v = (t < nb) ? bsum[t] : 0;
    ts[t] = v;
    __syncthreads();
    for (int off = 1; off < 256; off <<= 1) {
        int add = (t >= off) ? ts[t - off] : 0;
        __syncthreads();
        ts[t] += add;
        __syncthreads();
    }
    if (t < nb) bsum[t] = ts[t] - v;
}

__global__ void scan3_kernel(const int* __restrict__ part, const int* __restrict__ bsum,
                             int* __restrict__ rowptr, int* __restrict__ cursor, int n, int E) {
    int i = blockIdx.x * blockDim.x + threadIdx.x;
    if (i < n) { int r = part[i] + bsum[i / SCAN_B]; rowptr[i] = r; cursor[i] = r; }
    if (i == 0) rowptr[n] = E;
}

// ---- bucket fill ----
__global__ void fill_kernel(const int* __restrict__ src, const int* __restrict__ dst,
                            int* __restrict__ cursor, int* __restrict__ csr_src, int E) {
    int e = blockIdx.x * blockDim.x + threadIdx.x;
    if (e < E) {
        int pos = atomicAdd(&cursor[dst[e]], 1);
        csr_src[pos] = src[e];
    }
}

// ---- layer 1: quarter-wave float4 gather (with dinv[s] fma) + lin1 + relu, store scaled ----
__global__ __launch_bounds__(256) void prop_lin1_kernel(
    const float4* __restrict__ x4, const int* __restrict__ rowptr,
    const int* __restrict__ csr_src, const float* __restrict__ dinv,
    const float* __restrict__ W1, const float* __restrict__ b1,
    float* __restrict__ h1s, int n) {
    __shared__ float sWT[F][F + 1];   // sWT[k][j] = W1[j][k]
    __shared__ float sIn[4][F];
    int tid = threadIdx.x;
    for (int i = tid; i < F * F; i += 256) sWT[i & 63][i >> 6] = W1[i];
    int w = tid >> 6, lane = tid & 63;
    int q = lane >> 4, m = lane & 15;
    int node = blockIdx.x * 4 + w;
    if (node < n) {
        int beg = rowptr[node], end = rowptr[node + 1];
        float4 a0 = make_float4(0.f, 0.f, 0.f, 0.f);
        float4 a1 = make_float4(0.f, 0.f, 0.f, 0.f);
        int p = beg;
        for (; p + 8 <= end; p += 8) {
            int s0 = csr_src[p + q];
            int s1 = csr_src[p + 4 + q];
            float d0 = dinv[s0], d1 = dinv[s1];
            float4 v0 = x4[(size_t)s0 * 16 + m];
            float4 v1 = x4[(size_t)s1 * 16 + m];
            a0.x = fmaf(d0, v0.x, a0.x); a0.y = fmaf(d0, v0.y, a0.y);
            a0.z = fmaf(d0, v0.z, a0.z); a0.w = fmaf(d0, v0.w, a0.w);
            a1.x = fmaf(d1, v1.x, a1.x); a1.y = fmaf(d1, v1.y, a1.y);
            a1.z = fmaf(d1, v1.z, a1.z); a1.w = fmaf(d1, v1.w, a1.w);
        }
        for (; p < end; p += 4) {
            int idx = p + q;
            if (idx < end) {
                int s = csr_src[idx];
                float ds = dinv[s];
                float4 v = x4[(size_t)s * 16 + m];
                a0.x = fmaf(ds, v.x, a0.x); a0.y = fmaf(ds, v.y, a0.y);
                a0.z = fmaf(ds, v.z, a0.z); a0.w = fmaf(ds, v.w, a0.w);
            }
        }
        a0.x += a1.x; a0.y += a1.y; a0.z += a1.z; a0.w += a1.w;
        a0.x += __shfl_xor(a0.x, 16); a0.y += __shfl_xor(a0.y, 16);
        a0.z += __shfl_xor(a0.z, 16); a0.w += __shfl_xor(a0.w, 16);
        a0.x += __shfl_xor(a0.x, 32); a0.y += __shfl_xor(a0.y, 32);
        a0.z += __shfl_xor(a0.z, 32); a0.w += __shfl_xor(a0.w, 32);
        if (q == 0) {
            float dd = dinv[node];
            float4 self = x4[(size_t)node * 16 + m];
            float4 r;
            r.x = dd * fmaf(dd, self.x, a0.x);
            r.y = dd * fmaf(dd, self.y, a0.y);
            r.z = dd * fmaf(dd, self.z, a0.z);
            r.w = dd * fmaf(dd, self.w, a0.w);
            *(float4*)&sIn[w][m * 4] = r;
        }
    }
    __syncthreads();
    if (node < n) {
        float acc = b1[lane];
#pragma unroll
        for (int k = 0; k < F; ++k) acc = fmaf(sIn[w][k], sWT[k][lane], acc);
        h1s[(size_t)node * F + lane] = dinv[node] * fmaxf(acc, 0.0f);
    }
}

// ---- layer 2+3: pure-add float4 gather of pre-scaled h1s + lin2 + relu + lin3 ----
__global__ __launch_bounds__(256) void prop_lin23_kernel(
    const float4* __restrict__ h1s4, const int* __restrict__ rowptr,
    const int* __restrict__ csr_src, const float* __restrict__ dinv,
    const float* __restrict__ W2, const float* __restrict__ b2,
    const float* __restrict__ W3, const float* __restrict__ b3,
    float* __restrict__ out, int n) {
    __shared__ float sW2T[F][F + 1];
    __shared__ float sW3T[F][C + 1];
    __shared__ float sIn[4][F];
    __shared__ float sH2[4][F];
    int tid = threadIdx.x;
    for (int i = tid; i < F * F; i += 256) sW2T[i & 63][i >> 6] = W2[i];
    for (int i = tid; i < C * F; i += 256) sW3T[i & 63][i >> 6] = W3[i];
    int w = tid >> 6, lane = tid & 63;
    int q = lane >> 4, m = lane & 15;
    int node = blockIdx.x * 4 + w;
    if (node < n) {
        int beg = rowptr[node], end = rowptr[node + 1];
        float4 a0 = make_float4(0.f, 0.f, 0.f, 0.f);
        float4 a1 = make_float4(0.f, 0.f, 0.f, 0.f);
        int p = beg;
        for (; p + 8 <= end; p += 8) {
            int s0 = csr_src[p + q];
            int s1 = csr_src[p + 4 + q];
            float4 v0 = h1s4[(size_t)s0 * 16 + m];
            float4 v1 = h1s4[(size_t)s1 * 16 + m];
            a0.x += v0.x; a0.y += v0.y; a0.z += v0.z; a0.w += v0.w;
            a1.x += v1.x; a1.y += v1.y; a1.z += v1.z; a1.w += v1.w;
        }
        for (; p < end; p += 4) {
            int idx = p + q;
            if (idx < end) {
                int s = csr_src[idx];
                float4 v = h1s4[(size_t)s * 16 + m];
                a0.x += v.x; a0.y += v.y; a0.z += v.z; a0.w += v.w;
            }
        }
        a0.x += a1.x; a0.y += a1.y; a0.z += a1.z; a0.w += a1.w;
        a0.x += __shfl_xor(a0.x, 16); a0.y += __shfl_xor(a0.y, 16);
        a0.z += __shfl_xor(a0.z, 16); a0.w += __shfl_xor(a0.w, 16);
        a0.x += __shfl_xor(a0.x, 32); a0.y += __shfl_xor(a0.y, 32);
        a0.z += __shfl_xor(a0.z, 32); a0.w += __shfl_xor(a0.w, 32);
        if (q == 0) {
            float dd = dinv[node];
            float4 self = h1s4[(size_t)node * 16 + m];
            float4 r;
            r.x = dd * (a0.x + self.x);
            r.y = dd * (a0.y + self.y);
            r.z = dd * (a0.z + self.z);
            r.w = dd * (a0.w + self.w);
            *(float4*)&sIn[w][m * 4] = r;
        }
    }
    __syncthreads();
    if (node < n) {
        float acc = b2[lane];
#pragma unroll
        for (int k = 0; k < F; ++k) acc = fmaf(sIn[w][k], sW2T[k][lane], acc);
        sH2[w][lane] = fmaxf(acc, 0.0f);
    }
    __syncthreads();
    if (node < n && lane < C) {
        float acc = b3[lane];
#pragma unroll
        for (int k = 0; k < F; ++k) acc = fmaf(sH2[w][k], sW3T[k][lane], acc);
        out[(size_t)node * C + lane] = acc;
    }
}

extern "C" void kernel_launch(void* const* d_in, const int* in_sizes, int n_in,
                              void* d_out, int out_size, void* d_ws, size_t ws_size,
                              hipStream_t stream) {
    const float* x  = (const float*)d_in[0];
    const int* edge = (const int*)d_in[1];
    const float* W1 = (const float*)d_in[2];
    const float* b1 = (const float*)d_in[3];
    const float* W2 = (const float*)d_in[4];
    const float* b2 = (const float*)d_in[5];
    const float* W3 = (const float*)d_in[6];
    const float* b3 = (const float*)d_in[7];
    float* out = (float*)d_out;

    int n = in_sizes[0] / F;        // 100000
    int E = in_sizes[1] / 2;        // 1600000
    const int* src = edge;
    const int* dst = edge + E;

    int nb = (n + SCAN_B - 1) / SCAN_B;

    char* ws = (char*)d_ws;
    size_t o = 0;
    auto alloc = [&](size_t bytes) { char* p = ws + o; o += (bytes + 255) & ~(size_t)255; return p; };
    int*   deg     = (int*)  alloc((size_t)n * 4);
    int*   part    = (int*)  alloc((size_t)n * 4);
    int*   bsum    = (int*)  alloc(256 * 4);
    int*   rowptr  = (int*)  alloc((size_t)(n + 1) * 4);
    int*   cursor  = (int*)  alloc((size_t)n * 4);
    int*   csr_src = (int*)  alloc((size_t)E * 4);
    float* dinv    = (float*)alloc((size_t)n * 4);
    float* h1s     = (float*)alloc((size_t)n * F * 4);

    hipMemsetAsync(deg, 0, (size_t)n * 4, stream);
    deg_kernel<<<(E / 4 + 255) / 256, 256, 0, stream>>>(dst, deg, E);
    dinv_kernel<<<(n + 255) / 256, 256, 0, stream>>>(deg, dinv, n);

    scan1_kernel<<<nb, 256, 0, stream>>>(deg, part, bsum, n);
    scan2_kernel<<<1, 256, 0, stream>>>(bsum, nb);
    scan3_kernel<<<(n + 255) / 256, 256, 0, stream>>>(part, bsum, rowptr, cursor, n, E);

    fill_kernel<<<(E + 255) / 256, 256, 0, stream>>>(src, dst, cursor, csr_src, E);

    prop_lin1_kernel<<<(n + 3) / 4, 256, 0, stream>>>(
        (const float4*)x, rowptr, csr_src, dinv, W1, b1, h1s, n);
    prop_lin23_kernel<<<(n + 3) / 4, 256, 0, stream>>>(
        (const float4*)h1s, rowptr, csr_src, dinv, W2, b2, W3, b3, out, n);
}